// Round 8
// baseline (101.745 us; speedup 1.0000x reference)
//
#include <hip/hip_runtime.h>
#include <hip/hip_fp16.h>
#include <math.h>

#define HEADS 8
#define DIM 32
#define NEG_SLOPE 0.2f

__device__ inline float2 u2f2(unsigned int u) {
    __half2 h = __builtin_bit_cast(__half2, u);
    return __half22float2(h);
}

// Kernel 1 (merged): blocks [0, nb_logits) do per-node logits + fp16 convert
// (one wave per node); blocks [nb_logits, ...) build the CSR rowptr from the
// sorted dst_idx (edge-parallel).
__global__ __launch_bounds__(256) void gat_prep_kernel(
    const float4* __restrict__ feat4,    // node row = 64 float4
    const float4* __restrict__ attn_l4,  // 64 float4 (8 heads x 8)
    const float4* __restrict__ attn_r4,
    float* __restrict__ el,
    float* __restrict__ er,
    uint2* __restrict__ feat_h2,         // node row = 64 uint2 (fp16)
    const int* __restrict__ dst,
    int* __restrict__ rowptr,
    int n_nodes, int n_edges, int nb_logits) {
    int b = blockIdx.x;
    if (b < nb_logits) {
        int wid = (b * 256 + threadIdx.x) >> 6;
        if (wid >= n_nodes) return;
        int lane = threadIdx.x & 63;
        int h = lane >> 3;
        int q = lane & 7;

        float4 al = attn_l4[lane];
        float4 ar = attn_r4[lane];
        float4 v  = feat4[(size_t)wid * 64 + lane];

        float sl = v.x * al.x + v.y * al.y + v.z * al.z + v.w * al.w;
        float sr = v.x * ar.x + v.y * ar.y + v.z * ar.z + v.w * ar.w;
#pragma unroll
        for (int off = 1; off < 8; off <<= 1) {
            sl += __shfl_xor(sl, off, 64);
            sr += __shfl_xor(sr, off, 64);
        }
        if (q == 0) {
            el[wid * HEADS + h] = sl;
            er[wid * HEADS + h] = sr;
        }
        uint2 o;
        o.x = __builtin_bit_cast(unsigned int, __floats2half2_rn(v.x, v.y));
        o.y = __builtin_bit_cast(unsigned int, __floats2half2_rn(v.z, v.w));
        feat_h2[(size_t)wid * 64 + lane] = o;
    } else {
        int e = (b - nb_logits) * 256 + threadIdx.x;
        if (e >= n_edges) return;
        int d = dst[e];
        int prev = (e > 0) ? dst[e - 1] : -1;
        for (int v = prev + 1; v <= d; ++v) rowptr[v] = e;
        if (e == n_edges - 1) {
            for (int v = d + 1; v <= n_nodes; ++v) rowptr[v] = n_edges;
        }
    }
}

// Kernel 2: PERSISTENT waves. Grid = ~8192 waves; each wave grid-strides over
// ~6 nodes, averaging Poisson-degree variance (kills the straggler tail).
// Per node: R7 scalarized body — readfirstlane'd segment bounds, uniform
// src_idx loads (SMEM path), 32-bit index math, unroll-8 predicated batches.
// No max subtraction (|s| <~ 45 fits f32; softmax ratio identical).
__global__ __launch_bounds__(256) void gat_aggregate_kernel(
    const uint2* __restrict__ feat_h,    // node row = 64 uint2 (4 halfs/lane)
    const float* __restrict__ el,
    const float* __restrict__ er,
    const int* __restrict__ src_idx,
    const int* __restrict__ rowptr,
    float4* __restrict__ out4,
    int n_nodes, int total_waves) {
    int wave0 = (blockIdx.x * blockDim.x + threadIdx.x) >> 6;
    int lane = threadIdx.x & 63;
    int h = lane >> 3;

    for (int vraw = wave0; vraw < n_nodes; vraw += total_waves) {
        int v = __builtin_amdgcn_readfirstlane(vraw);
        int start = __builtin_amdgcn_readfirstlane(rowptr[v]);
        int end   = __builtin_amdgcn_readfirstlane(rowptr[v + 1]);

        unsigned obase = ((unsigned)v << 6) + (unsigned)lane;
        if (start == end) {
            out4[obase] = make_float4(0.f, 0.f, 0.f, 0.f);
            continue;
        }
        int endm1 = end - 1;
        float er_vh = er[((unsigned)v << 3) + h];

        float denomA = 0.f, denomB = 0.f;
        float4 acc0 = make_float4(0.f, 0.f, 0.f, 0.f);
        float4 acc1 = make_float4(0.f, 0.f, 0.f, 0.f);

        for (int e = start; e < end; e += 8) {
            int   idx[8];
            uint2 fr[8];
            float elv[8];
#pragma unroll
            for (int i = 0; i < 8; ++i) {
                int ee = (e + i < endm1) ? (e + i) : endm1;   // scalar clamp
                idx[i] = src_idx[ee];                          // uniform -> s_load
            }
#pragma unroll
            for (int i = 0; i < 8; ++i) {
                fr[i] = feat_h[((unsigned)idx[i] << 6) + (unsigned)lane];
            }
#pragma unroll
            for (int i = 0; i < 8; ++i) {
                elv[i] = el[((unsigned)idx[i] << 3) + (unsigned)h];
            }
#pragma unroll
            for (int i = 0; i < 8; ++i) {
                float s = elv[i] + er_vh;
                s = fmaxf(s, NEG_SLOPE * s);          // leaky relu
                if (e + i > endm1) s = -INFINITY;     // tail slot -> w = 0
                float w = __expf(s);
                float2 lo = u2f2(fr[i].x);
                float2 hi = u2f2(fr[i].y);
                if (i & 1) {
                    denomB += w;
                    acc1.x += w * lo.x; acc1.y += w * lo.y;
                    acc1.z += w * hi.x; acc1.w += w * hi.y;
                } else {
                    denomA += w;
                    acc0.x += w * lo.x; acc0.y += w * lo.y;
                    acc0.z += w * hi.x; acc0.w += w * hi.y;
                }
            }
        }
        float inv = 1.f / (denomA + denomB);
        float4 r;
        r.x = (acc0.x + acc1.x) * inv;
        r.y = (acc0.y + acc1.y) * inv;
        r.z = (acc0.z + acc1.z) * inv;
        r.w = (acc0.w + acc1.w) * inv;
        out4[obase] = r;
    }
}

extern "C" void kernel_launch(void* const* d_in, const int* in_sizes, int n_in,
                              void* d_out, int out_size, void* d_ws, size_t ws_size,
                              hipStream_t stream) {
    const float* feat   = (const float*)d_in[0];
    const float* attn_l = (const float*)d_in[1];
    const float* attn_r = (const float*)d_in[2];
    const int*   src    = (const int*)d_in[3];
    const int*   dst    = (const int*)d_in[4];
    float* out = (float*)d_out;

    int n_edges = in_sizes[3];
    int n_nodes = out_size / (HEADS * DIM);
    int nh = n_nodes * HEADS;

    // Workspace: el[nh] | er[nh] | rowptr[n_nodes+1] | (align) | feat_h[nh*32] fp16
    char* ws = (char*)d_ws;
    float* el = (float*)ws;                       ws += (size_t)nh * 4;
    float* er = (float*)ws;                       ws += (size_t)nh * 4;
    int* rowptr = (int*)ws;                       ws += (size_t)(n_nodes + 1) * 4;
    ws = (char*)(((uintptr_t)ws + 15) & ~(uintptr_t)15);
    uint2* feat_h2 = (uint2*)ws;

    int nb_logits = (n_nodes + 3) / 4;            // 1 wave/node, 4 per block
    int nb_rowptr = (n_edges + 255) / 256;
    hipLaunchKernelGGL(gat_prep_kernel,
                       dim3(nb_logits + nb_rowptr), dim3(256), 0, stream,
                       (const float4*)feat, (const float4*)attn_l,
                       (const float4*)attn_r, el, er, feat_h2,
                       dst, rowptr, n_nodes, n_edges, nb_logits);

    // Persistent aggregate: 2048 blocks x 4 waves = 8192 waves, grid-stride.
    int blocks = 2048;
    int total_waves = blocks * 4;
    hipLaunchKernelGGL(gat_aggregate_kernel,
                       dim3(blocks), dim3(256), 0, stream,
                       (const uint2*)feat_h2, el, er, src, rowptr, (float4*)out,
                       n_nodes, total_waves);
}